// Round 6
// baseline (220.181 us; speedup 1.0000x reference)
//
#include <hip/hip_runtime.h>
#include <hip/hip_bf16.h>

// ---- types ----
typedef __attribute__((ext_vector_type(8))) short short8_t;   // 8 x bf16 (4 VGPR)
typedef __attribute__((ext_vector_type(4))) float f32x4;      // MFMA acc

__device__ __forceinline__ short f2bf(float f) {
    union { float f; unsigned u; } v; v.f = f;
    unsigned r = (v.u + 0x7FFFu + ((v.u >> 16) & 1u)) >> 16;  // RNE
    return (short)r;
}

// Geometry: x[8][256][256][256] fp32. u = c in [0,128), v = c in [128,256).
// M = 262144 rows of 256. Per-batch rows = 32768. 16384 16-row tiles.
#define N_PER_BATCH 8388608.0f

// ---------------- kernel 1: per-block partial sums over v ----------------
__global__ __launch_bounds__(256) void stats_partial(const float* __restrict__ x,
                                                     float2* __restrict__ partials) {
    int bid = blockIdx.x;
    int batch = bid >> 8;
    int blk   = bid & 255;
    const float* base = x + ((size_t)batch << 24) + (1u << 23) + ((size_t)blk << 15);
    int tid = threadIdx.x;
    float s1 = 0.f, s2 = 0.f;
    #pragma unroll
    for (int i = 0; i < 32; ++i) {
        float4 v = *reinterpret_cast<const float4*>(base + (size_t)(i * 256 + tid) * 4);
        s1 += v.x + v.y + v.z + v.w;
        s2 += v.x * v.x + v.y * v.y + v.z * v.z + v.w * v.w;
    }
    #pragma unroll
    for (int off = 32; off; off >>= 1) {
        s1 += __shfl_down(s1, off);
        s2 += __shfl_down(s2, off);
    }
    __shared__ float2 red[4];
    if ((tid & 63) == 0) red[tid >> 6] = make_float2(s1, s2);
    __syncthreads();
    if (tid == 0) {
        float a1 = 0.f, a2 = 0.f;
        #pragma unroll
        for (int w = 0; w < 4; ++w) { a1 += red[w].x; a2 += red[w].y; }
        partials[bid] = make_float2(a1, a2);
    }
}

// ---------------- kernel 1b: finalize per-batch mean/rstd ----------------
__global__ __launch_bounds__(256) void stats_final(const float2* __restrict__ partials,
                                                   float2* __restrict__ stats) {
    int batch = blockIdx.x;
    int tid = threadIdx.x;
    float2 p = partials[(batch << 8) + tid];
    float s1 = p.x, s2 = p.y;
    #pragma unroll
    for (int off = 32; off; off >>= 1) {
        s1 += __shfl_down(s1, off);
        s2 += __shfl_down(s2, off);
    }
    __shared__ float2 red[4];
    if ((tid & 63) == 0) red[tid >> 6] = make_float2(s1, s2);
    __syncthreads();
    if (tid == 0) {
        float a1 = 0.f, a2 = 0.f;
        #pragma unroll
        for (int w = 0; w < 4; ++w) { a1 += red[w].x; a2 += red[w].y; }
        float mean = a1 / N_PER_BATCH;
        float var  = a2 / N_PER_BATCH - mean * mean;
        stats[batch] = make_float2(mean, rsqrtf(var + 1e-5f));
    }
}

// ---------------- kernel 2: fused normalize + GEMM + gate ----------------
// W (bf16, XOR-swizzled) staged ONCE into 128 KiB LDS; bias+1 in 1 KiB LDS.
// After the single staging barrier, the 16 waves are fully independent:
// wave gw processes 16-row tiles (16383-gw-4096*it), it=0..3, in REVERSE
// batch order (L3 reuse of the stats pass's v read). Per tile: global v ->
// normalized bf16 A-frags in regs; 16 col-tiles x 8 MFMA with B-frags from
// LDS (swizzle elem^((row&7)<<3) => conflict-free b128); quad-transpose;
// fused u-load / out-store as float4. No barriers in the main loop.
__global__ __launch_bounds__(1024) void fused_gemm(const float* __restrict__ x,
                                                   const float* __restrict__ W,
                                                   const float* __restrict__ bias,
                                                   const float2* __restrict__ stats,
                                                   float* __restrict__ out) {
    __shared__ short wl[65536];    // 128 KiB: W[row][col^((row&7)<<3)] bf16
    __shared__ float bp1[256];     // bias + 1
    const int tid  = threadIdx.x;
    const int wid  = tid >> 6;
    const int lane = tid & 63;
    const int l15  = lane & 15;
    const int l4   = lane >> 4;
    const int q    = l15 & 3;
    const int qg   = l15 >> 2;

    // ---- stage W -> LDS (swizzled): 16384 float4, 16 per thread ----
    #pragma unroll
    for (int i = 0; i < 16; ++i) {
        int idx = tid + (i << 10);
        int row = idx >> 6;                 // 64 float4 per row
        int c0  = (idx & 63) << 2;
        float4 w4 = reinterpret_cast<const float4*>(W)[idx];
        short4 s;
        s.x = f2bf(w4.x); s.y = f2bf(w4.y); s.z = f2bf(w4.z); s.w = f2bf(w4.w);
        int sw = (row << 8) + (c0 ^ ((row & 7) << 3));
        *reinterpret_cast<short4*>(&wl[sw]) = s;
    }
    if (tid < 64) {
        float4 b4 = reinterpret_cast<const float4*>(bias)[tid];
        bp1[tid * 4 + 0] = b4.x + 1.f;
        bp1[tid * 4 + 1] = b4.y + 1.f;
        bp1[tid * 4 + 2] = b4.z + 1.f;
        bp1[tid * 4 + 3] = b4.w + 1.f;
    }
    __syncthreads();   // the only block-wide barrier

    const int gw  = (blockIdx.x << 4) + wid;          // 0..4095
    const int xsw = (l15 & 7) << 3;                   // col&7 == l15&7 (nc*16 ≡ 0 mod 8)

    for (int it = 0; it < 4; ++it) {
        const int tile = 16383 - gw - (it << 12);     // reverse order
        const size_t row0 = (size_t)tile << 4;
        const int bi = (int)(row0 >> 15);
        const size_t rowb = row0 & 32767;
        const float2 ms = stats[bi];
        const float mean = ms.x, rstd = ms.y;

        const float* vrow  = x + ((size_t)bi << 24) + (1u << 23) + (rowb << 8)
                               + (size_t)l15 * 256 + (l4 << 3);
        const float* ubase = x + ((size_t)bi << 24) + (rowb << 8);
        float*       obase = out + (row0 << 8);

        // ---- A-frags: lane holds v[l15][kb*32 + l4*8 + j], normalized ----
        short8_t af[8];
        #pragma unroll
        for (int kb = 0; kb < 8; ++kb) {
            float4 p0 = *reinterpret_cast<const float4*>(vrow + kb * 32);
            float4 p1 = *reinterpret_cast<const float4*>(vrow + kb * 32 + 4);
            short8_t a;
            a[0] = f2bf((p0.x - mean) * rstd);
            a[1] = f2bf((p0.y - mean) * rstd);
            a[2] = f2bf((p0.z - mean) * rstd);
            a[3] = f2bf((p0.w - mean) * rstd);
            a[4] = f2bf((p1.x - mean) * rstd);
            a[5] = f2bf((p1.y - mean) * rstd);
            a[6] = f2bf((p1.z - mean) * rstd);
            a[7] = f2bf((p1.w - mean) * rstd);
            af[kb] = a;
        }

        // epilogue lane offset: row = l4*4+q, colgroup base = qg*4
        const size_t eo0 = (size_t)(l4 * 4 + q) * 256 + (qg << 2);

        // u prefetched one col-tile ahead
        float4 u4 = *reinterpret_cast<const float4*>(ubase + eo0);

        #pragma unroll 2
        for (int nc = 0; nc < 16; ++nc) {
            const int ncn = (nc < 15) ? nc + 1 : 15;
            float4 u_next = *reinterpret_cast<const float4*>(ubase + eo0 + (ncn << 4));

            // ---- 8 MFMAs, B-frags from swizzled LDS ----
            const int wb = ((nc << 4) + l15) << 8;    // row base (shorts)
            f32x4 acc = {0.f, 0.f, 0.f, 0.f};
            #pragma unroll
            for (int kb = 0; kb < 8; ++kb) {
                const int off = wb + ((((kb << 5) + (l4 << 3)) ^ xsw));
                short8_t b = *reinterpret_cast<const short8_t*>(&wl[off]);
                acc = __builtin_amdgcn_mfma_f32_16x16x32_bf16(af[kb], b, acc, 0, 0, 0);
            }

            // ---- 4x4 transpose within lane quads ----
            float a0 = acc[0], a1 = acc[1], a2 = acc[2], a3 = acc[3];
            float s0 = __shfl_xor(a1, 1), s1 = __shfl_xor(a0, 1);
            float s2 = __shfl_xor(a3, 1), s3 = __shfl_xor(a2, 1);
            const bool qb0 = (q & 1);
            float w0 = qb0 ? s0 : a0;
            float w1 = qb0 ? a1 : s1;
            float w2 = qb0 ? s2 : a2;
            float w3 = qb0 ? a3 : s3;
            float t0 = __shfl_xor(w2, 2), t1 = __shfl_xor(w3, 2);
            float t2 = __shfl_xor(w0, 2), t3 = __shfl_xor(w1, 2);
            const bool qb1 = (q & 2);
            float x0 = qb1 ? t0 : w0;
            float x1 = qb1 ? t1 : w1;
            float x2 = qb1 ? w2 : t2;
            float x3 = qb1 ? w3 : t3;

            // ---- epilogue: out = u * (y + b + 1), bias from LDS (broadcast) ----
            float4 bq = *reinterpret_cast<const float4*>(&bp1[(nc << 4) + (qg << 2)]);
            const size_t uo = eo0 + (nc << 4);
            float4 o;
            o.x = u4.x * (x0 + bq.x);
            o.y = u4.y * (x1 + bq.y);
            o.z = u4.z * (x2 + bq.z);
            o.w = u4.w * (x3 + bq.w);
            *reinterpret_cast<float4*>(obase + uo) = o;
            u4 = u_next;
        }
    }
}

extern "C" void kernel_launch(void* const* d_in, const int* in_sizes, int n_in,
                              void* d_out, int out_size, void* d_ws, size_t ws_size,
                              hipStream_t stream) {
    const float* x    = (const float*)d_in[0];
    const float* W    = (const float*)d_in[1];
    const float* bias = (const float*)d_in[2];
    float* out = (float*)d_out;

    float2* partials = (float2*)d_ws;                       // 2048 * 8 B
    float2* stats    = (float2*)((char*)d_ws + 16384);      // 8 * 8 B

    stats_partial<<<2048, 256, 0, stream>>>(x, partials);
    stats_final<<<8, 256, 0, stream>>>(partials, stats);
    fused_gemm<<<256, 1024, 0, stream>>>(x, W, bias, stats, out);
}

// Round 8
// 201.913 us; speedup vs baseline: 1.0905x; 1.0905x over previous
//
#include <hip/hip_runtime.h>
#include <hip/hip_bf16.h>

// ---- types ----
typedef __attribute__((ext_vector_type(8))) short short8_t;   // 8 x bf16 (4 VGPR)
typedef __attribute__((ext_vector_type(4))) float f32x4;      // MFMA acc / native float4

__device__ __forceinline__ short f2bf(float f) {
    union { float f; unsigned u; } v; v.f = f;
    unsigned r = (v.u + 0x7FFFu + ((v.u >> 16) & 1u)) >> 16;  // RNE
    return (short)r;
}

// non-temporal float4 helpers (native clang vector type — HIP_vector_type
// structs are rejected by the builtin). Keep u/out out of the Infinity Cache
// so the v re-read (resident in L3 from stats_partial) survives.
__device__ __forceinline__ f32x4 ntload4(const float* p) {
    return __builtin_nontemporal_load(reinterpret_cast<const f32x4*>(p));
}
__device__ __forceinline__ void ntstore4(float* p, f32x4 v) {
    __builtin_nontemporal_store(v, reinterpret_cast<f32x4*>(p));
}

// Geometry: x[8][256][256][256] fp32. u = c in [0,128), v = c in [128,256).
// M = 262144 rows of 256. Per-batch rows = 32768.
#define N_PER_BATCH 8388608.0f
#define LDR 264                  // padded LDS row (bf16): A-reads 2-way banks (free)

// ---------------- kernel 1: per-block partial sums over v ----------------
// Regular (caching) loads on purpose: this pass populates L3 with v.
__global__ __launch_bounds__(256) void stats_partial(const float* __restrict__ x,
                                                     float2* __restrict__ partials) {
    int bid = blockIdx.x;
    int batch = bid >> 8;
    int blk   = bid & 255;
    const float* base = x + ((size_t)batch << 24) + (1u << 23) + ((size_t)blk << 15);
    int tid = threadIdx.x;
    float s1 = 0.f, s2 = 0.f;
    #pragma unroll
    for (int i = 0; i < 32; ++i) {
        float4 v = *reinterpret_cast<const float4*>(base + (size_t)(i * 256 + tid) * 4);
        s1 += v.x + v.y + v.z + v.w;
        s2 += v.x * v.x + v.y * v.y + v.z * v.z + v.w * v.w;
    }
    #pragma unroll
    for (int off = 32; off; off >>= 1) {
        s1 += __shfl_down(s1, off);
        s2 += __shfl_down(s2, off);
    }
    __shared__ float2 red[4];
    if ((tid & 63) == 0) red[tid >> 6] = make_float2(s1, s2);
    __syncthreads();
    if (tid == 0) {
        float a1 = 0.f, a2 = 0.f;
        #pragma unroll
        for (int w = 0; w < 4; ++w) { a1 += red[w].x; a2 += red[w].y; }
        partials[bid] = make_float2(a1, a2);
    }
}

// ---------------- kernel 1b: finalize per-batch mean/rstd ----------------
__global__ __launch_bounds__(256) void stats_final(const float2* __restrict__ partials,
                                                   float2* __restrict__ stats) {
    int batch = blockIdx.x;
    int tid = threadIdx.x;
    float2 p = partials[(batch << 8) + tid];
    float s1 = p.x, s2 = p.y;
    #pragma unroll
    for (int off = 32; off; off >>= 1) {
        s1 += __shfl_down(s1, off);
        s2 += __shfl_down(s2, off);
    }
    __shared__ float2 red[4];
    if ((tid & 63) == 0) red[tid >> 6] = make_float2(s1, s2);
    __syncthreads();
    if (tid == 0) {
        float a1 = 0.f, a2 = 0.f;
        #pragma unroll
        for (int w = 0; w < 4; ++w) { a1 += red[w].x; a2 += red[w].y; }
        float mean = a1 / N_PER_BATCH;
        float var  = a2 / N_PER_BATCH - mean * mean;
        stats[batch] = make_float2(mean, rsqrtf(var + 1e-5f));
    }
}

// ---------------- kernel 2: fused normalize + GEMM + gate ----------------
// 1024 thr = 16 waves, 1 block/CU. Wave w owns cols [w*16, w*16+16) (32 VGPR
// B-frags). Per 16-row tile: reg-staged normalized bf16 v -> double-buffered
// LDS; 8 MFMAs/wave; quad-transpose epilogue. v loads CACHED (L3 hits from
// the stats pass); u loads and out stores NON-TEMPORAL so they don't evict v.
// v prefetched 2 tiles ahead, u 1 tile ahead; raw s_barrier with lgkmcnt-only
// drain keeps global loads in flight across the per-tile barrier.
__global__ __launch_bounds__(1024, 4) void fused_gemm(const float* __restrict__ x,
                                                      const float* __restrict__ W,
                                                      const float* __restrict__ bias,
                                                      const float2* __restrict__ stats,
                                                      float* __restrict__ out) {
    __shared__ short vt[2][16 * LDR];   // 16896 B
    const int tid  = threadIdx.x;
    const int wid  = tid >> 6;
    const int lane = tid & 63;
    const int l15  = lane & 15;
    const int l4   = lane >> 4;
    const int q    = l15 & 3;
    const int qg   = l15 >> 2;

    const int bi = blockIdx.x >> 5;          // 32 blocks per batch
    const float2 ms = stats[bi];
    const float mean = ms.x, rstd = ms.y;

    // ---- B fragments: W[col][k], col = wid*16 + l15, k = kb*32 + l4*8 + j ----
    short8_t bfrag[8];
    {
        const float* wbase = W + (size_t)(wid * 16 + l15) * 256 + (l4 << 3);
        #pragma unroll
        for (int kb = 0; kb < 8; ++kb) {
            float4 p0 = *reinterpret_cast<const float4*>(wbase + kb * 32);
            float4 p1 = *reinterpret_cast<const float4*>(wbase + kb * 32 + 4);
            short8_t s;
            s[0] = f2bf(p0.x); s[1] = f2bf(p0.y); s[2] = f2bf(p0.z); s[3] = f2bf(p0.w);
            s[4] = f2bf(p1.x); s[5] = f2bf(p1.y); s[6] = f2bf(p1.z); s[7] = f2bf(p1.w);
            bfrag[kb] = s;
        }
    }
    // bias (+1) for post-transpose cols: wid*16 + qg*4 + (0..3)
    float4 bq = *reinterpret_cast<const float4*>(bias + wid * 16 + (qg << 2));
    bq.x += 1.f; bq.y += 1.f; bq.z += 1.f; bq.w += 1.f;

    // ---- block's rows: 64 tiles x 16 rows = 1024 rows within batch bi ----
    const size_t rowb = (size_t)(blockIdx.x & 31) * 1024;
    const float* vbase = x + ((size_t)bi << 24) + (1u << 23) + (rowb << 8);
    const float* ubase = x + ((size_t)bi << 24) + (rowb << 8);
    float*       obase = out + (((size_t)bi * 32768 + rowb) << 8);

    // staging role: 1024 float4 per tile / 1024 thr = 1 each
    const int   srow = tid >> 6;
    const int   scol = (tid & 63) << 2;
    const size_t goff = (size_t)srow * 256 + scol;
    const int   ldsw = srow * LDR + scol;

    // per-wave epilogue offset: row = l4*4+q, cols = wid*16 + qg*4
    const size_t eoff = (size_t)(l4 * 4 + q) * 256 + wid * 16 + (qg << 2);

    // A-frag LDS base: row = l15, k-offset = l4*8
    const int aoff = l15 * LDR + (l4 << 3);

    const int nt = 64;

    // ---- prologue: stage tile 0; start v(1), u(0) ----
    float4 v0 = *reinterpret_cast<const float4*>(vbase + goff);
    float4 vA = *reinterpret_cast<const float4*>(vbase + (1ull << 12) + goff);  // v(1)
    f32x4 uA = ntload4(ubase + eoff);                                           // u(0)
    {
        short4 s;
        s.x = f2bf((v0.x - mean) * rstd); s.y = f2bf((v0.y - mean) * rstd);
        s.z = f2bf((v0.z - mean) * rstd); s.w = f2bf((v0.w - mean) * rstd);
        *reinterpret_cast<short4*>(&vt[0][ldsw]) = s;
    }
    asm volatile("s_waitcnt lgkmcnt(0)" ::: "memory");
    __builtin_amdgcn_s_barrier();

    for (int t = 0; t < nt; ++t) {
        const int cur = t & 1;
        const int t2 = (t + 2 < nt) ? t + 2 : nt - 1;
        const int t1 = (t + 1 < nt) ? t + 1 : nt - 1;
        // issue deep prefetches first (stay in flight across the barrier)
        float4 vB = *reinterpret_cast<const float4*>(vbase + ((size_t)t2 << 12) + goff);
        f32x4 uB = ntload4(ubase + ((size_t)t1 << 12) + eoff);

        // ---- MFMA over K=256 ----
        f32x4 acc = {0.f, 0.f, 0.f, 0.f};
        #pragma unroll
        for (int kb = 0; kb < 8; ++kb) {
            short8_t a = *reinterpret_cast<const short8_t*>(&vt[cur][aoff + kb * 32]);
            acc = __builtin_amdgcn_mfma_f32_16x16x32_bf16(a, bfrag[kb], acc, 0, 0, 0);
        }

        // ---- 4x4 transpose within lane quads: reg r <-> lane q ----
        float a0 = acc[0], a1 = acc[1], a2 = acc[2], a3 = acc[3];
        float s0 = __shfl_xor(a1, 1), s1 = __shfl_xor(a0, 1);
        float s2 = __shfl_xor(a3, 1), s3 = __shfl_xor(a2, 1);
        const bool qb0 = (q & 1);
        float w0 = qb0 ? s0 : a0;
        float w1 = qb0 ? a1 : s1;
        float w2 = qb0 ? s2 : a2;
        float w3 = qb0 ? a3 : s3;
        float t0 = __shfl_xor(w2, 2), t1v = __shfl_xor(w3, 2);
        float t2v = __shfl_xor(w0, 2), t3 = __shfl_xor(w1, 2);
        const bool qb1 = (q & 2);
        float x0 = qb1 ? t0 : w0;
        float x1 = qb1 ? t1v : w1;
        float x2 = qb1 ? w2 : t2v;
        float x3 = qb1 ? w3 : t3;

        // ---- epilogue: out = u * (y + b + 1), non-temporal store ----
        const size_t uo = ((size_t)t << 12) + eoff;
        f32x4 o;
        o[0] = uA[0] * (x0 + bq.x);
        o[1] = uA[1] * (x1 + bq.y);
        o[2] = uA[2] * (x2 + bq.z);
        o[3] = uA[3] * (x3 + bq.w);
        ntstore4(obase + uo, o);

        // ---- stage tile t+1 (vA) into other buffer ----
        short4 sn;
        sn.x = f2bf((vA.x - mean) * rstd); sn.y = f2bf((vA.y - mean) * rstd);
        sn.z = f2bf((vA.z - mean) * rstd); sn.w = f2bf((vA.w - mean) * rstd);
        *reinterpret_cast<short4*>(&vt[cur ^ 1][ldsw]) = sn;

        // raw barrier: drain LDS only, keep global loads in flight
        asm volatile("s_waitcnt lgkmcnt(0)" ::: "memory");
        __builtin_amdgcn_s_barrier();

        vA = vB; uA = uB;
    }
}

extern "C" void kernel_launch(void* const* d_in, const int* in_sizes, int n_in,
                              void* d_out, int out_size, void* d_ws, size_t ws_size,
                              hipStream_t stream) {
    const float* x    = (const float*)d_in[0];
    const float* W    = (const float*)d_in[1];
    const float* bias = (const float*)d_in[2];
    float* out = (float*)d_out;

    float2* partials = (float2*)d_ws;                       // 2048 * 8 B
    float2* stats    = (float2*)((char*)d_ws + 16384);      // 8 * 8 B

    stats_partial<<<2048, 256, 0, stream>>>(x, partials);
    stats_final<<<8, 256, 0, stream>>>(partials, stats);
    fused_gemm<<<256, 1024, 0, stream>>>(x, W, bias, stats, out);
}

// Round 9
// 184.303 us; speedup vs baseline: 1.1947x; 1.0955x over previous
//
#include <hip/hip_runtime.h>
#include <hip/hip_bf16.h>

// ---- types ----
typedef __attribute__((ext_vector_type(8))) short short8_t;   // 8 x bf16 (4 VGPR)
typedef __attribute__((ext_vector_type(4))) float f32x4;      // MFMA acc / native float4

__device__ __forceinline__ short f2bf(float f) {
    union { float f; unsigned u; } v; v.f = f;
    unsigned r = (v.u + 0x7FFFu + ((v.u >> 16) & 1u)) >> 16;  // RNE
    return (short)r;
}

// non-temporal float4 helpers (native clang vector type). u/out bypass the
// Infinity Cache so v (written into L3 by stats_partial) survives for re-read.
__device__ __forceinline__ f32x4 ntload4(const float* p) {
    return __builtin_nontemporal_load(reinterpret_cast<const f32x4*>(p));
}
__device__ __forceinline__ void ntstore4(float* p, f32x4 v) {
    __builtin_nontemporal_store(v, reinterpret_cast<f32x4*>(p));
}

// Geometry: x[8][256][256][256] fp32. u = c in [0,128), v = c in [128,256).
// M = 262144 rows of 256. 16384 16-row tiles; 2048 tiles per batch.
#define N_PER_BATCH 8388608.0f
#define LDR 264                  // padded LDS row (bf16): A-reads 2-way banks (free)

// ---------------- kernel 1: per-block partial sums over v ----------------
// Regular (caching) loads on purpose: this pass populates L3 with v.
__global__ __launch_bounds__(256) void stats_partial(const float* __restrict__ x,
                                                     float2* __restrict__ partials) {
    int bid = blockIdx.x;
    int batch = bid >> 8;
    int blk   = bid & 255;
    const float* base = x + ((size_t)batch << 24) + (1u << 23) + ((size_t)blk << 15);
    int tid = threadIdx.x;
    float s1 = 0.f, s2 = 0.f;
    #pragma unroll
    for (int i = 0; i < 32; ++i) {
        float4 v = *reinterpret_cast<const float4*>(base + (size_t)(i * 256 + tid) * 4);
        s1 += v.x + v.y + v.z + v.w;
        s2 += v.x * v.x + v.y * v.y + v.z * v.z + v.w * v.w;
    }
    #pragma unroll
    for (int off = 32; off; off >>= 1) {
        s1 += __shfl_down(s1, off);
        s2 += __shfl_down(s2, off);
    }
    __shared__ float2 red[4];
    if ((tid & 63) == 0) red[tid >> 6] = make_float2(s1, s2);
    __syncthreads();
    if (tid == 0) {
        float a1 = 0.f, a2 = 0.f;
        #pragma unroll
        for (int w = 0; w < 4; ++w) { a1 += red[w].x; a2 += red[w].y; }
        partials[bid] = make_float2(a1, a2);
    }
}

// ---------------- kernel 1b: finalize per-batch mean/rstd ----------------
__global__ __launch_bounds__(256) void stats_final(const float2* __restrict__ partials,
                                                   float2* __restrict__ stats) {
    int batch = blockIdx.x;
    int tid = threadIdx.x;
    float2 p = partials[(batch << 8) + tid];
    float s1 = p.x, s2 = p.y;
    #pragma unroll
    for (int off = 32; off; off >>= 1) {
        s1 += __shfl_down(s1, off);
        s2 += __shfl_down(s2, off);
    }
    __shared__ float2 red[4];
    if ((tid & 63) == 0) red[tid >> 6] = make_float2(s1, s2);
    __syncthreads();
    if (tid == 0) {
        float a1 = 0.f, a2 = 0.f;
        #pragma unroll
        for (int w = 0; w < 4; ++w) { a1 += red[w].x; a2 += red[w].y; }
        float mean = a1 / N_PER_BATCH;
        float var  = a2 / N_PER_BATCH - mean * mean;
        stats[batch] = make_float2(mean, rsqrtf(var + 1e-5f));
    }
}

// ---------------- kernel 2: fused normalize + GEMM + gate ----------------
// 1024 thr = 16 waves. REVERSE GRID-STRIDED tile walk: block b does tiles
// 16383-(b+s*256), s=0..63. At s=0 the whole GPU touches the freshest v
// lines in L3 (the stats pass read them last) and walks backward through
// progressively older ones; at any instant all blocks cluster in one ~64 MB
// span per stream (HBM row locality). u loads / out stores non-temporal.
// v prefetched 2 steps ahead, u 1 step; lgkmcnt-only barrier.
__global__ __launch_bounds__(1024, 4) void fused_gemm(const float* __restrict__ x,
                                                      const float* __restrict__ W,
                                                      const float* __restrict__ bias,
                                                      const float2* __restrict__ stats,
                                                      float* __restrict__ out) {
    __shared__ short vt[2][16 * LDR];   // 16896 B
    const int tid  = threadIdx.x;
    const int wid  = tid >> 6;
    const int lane = tid & 63;
    const int l15  = lane & 15;
    const int l4   = lane >> 4;
    const int q    = l15 & 3;
    const int qg   = l15 >> 2;

    // ---- B fragments: W[col][k], col = wid*16 + l15, k = kb*32 + l4*8 + j ----
    short8_t bfrag[8];
    {
        const float* wbase = W + (size_t)(wid * 16 + l15) * 256 + (l4 << 3);
        #pragma unroll
        for (int kb = 0; kb < 8; ++kb) {
            float4 p0 = *reinterpret_cast<const float4*>(wbase + kb * 32);
            float4 p1 = *reinterpret_cast<const float4*>(wbase + kb * 32 + 4);
            short8_t s;
            s[0] = f2bf(p0.x); s[1] = f2bf(p0.y); s[2] = f2bf(p0.z); s[3] = f2bf(p0.w);
            s[4] = f2bf(p1.x); s[5] = f2bf(p1.y); s[6] = f2bf(p1.z); s[7] = f2bf(p1.w);
            bfrag[kb] = s;
        }
    }
    // bias (+1) for post-transpose cols: wid*16 + qg*4 + (0..3)
    float4 bq = *reinterpret_cast<const float4*>(bias + wid * 16 + (qg << 2));
    bq.x += 1.f; bq.y += 1.f; bq.z += 1.f; bq.w += 1.f;

    // staging role: 1024 float4 per tile / 1024 thr = 1 each
    const int   srow = tid >> 6;
    const int   scol = (tid & 63) << 2;
    const size_t goff = (size_t)srow * 256 + scol;   // within-tile v offset
    const int   ldsw = srow * LDR + scol;

    // per-wave epilogue offset: row = l4*4+q, cols = wid*16 + qg*4
    const size_t eoff = (size_t)(l4 * 4 + q) * 256 + wid * 16 + (qg << 2);

    // A-frag LDS base: row = l15, k-offset = l4*8
    const int aoff = l15 * LDR + (l4 << 3);

    const int b = blockIdx.x;
    // tile index for step s: 16383 - (b + s*256)
    // v element address of tile T: x + (T>>11)<<24 + 2^23 + ((T&2047)<<12)
    // u element address of tile T: x + (T>>11)<<24 +        ((T&2047)<<12)
    // out element address:         out + (T<<12)
    #define TILE(s) (16383 - (b + ((s) << 8)))
    #define VADDR(T) (x + ((size_t)((T) >> 11) << 24) + (1u << 23) + ((size_t)((T) & 2047) << 12))
    #define UADDR(T) (x + ((size_t)((T) >> 11) << 24) + ((size_t)((T) & 2047) << 12))

    // ---- prologue: stage tile(0); start v(1), u(0) ----
    {
        const int T0 = TILE(0);
        const float2 ms0 = stats[T0 >> 11];
        float4 v0 = *reinterpret_cast<const float4*>(VADDR(T0) + goff);
        short4 s;
        s.x = f2bf((v0.x - ms0.x) * ms0.y); s.y = f2bf((v0.y - ms0.x) * ms0.y);
        s.z = f2bf((v0.z - ms0.x) * ms0.y); s.w = f2bf((v0.w - ms0.x) * ms0.y);
        *reinterpret_cast<short4*>(&vt[0][ldsw]) = s;
    }
    const int T1i = TILE(1);
    float4 vA = *reinterpret_cast<const float4*>(VADDR(T1i) + goff);   // v of tile(1)
    f32x4 uA = ntload4(UADDR(TILE(0)) + eoff);                          // u of tile(0)
    asm volatile("s_waitcnt lgkmcnt(0)" ::: "memory");
    __builtin_amdgcn_s_barrier();

    for (int s = 0; s < 64; ++s) {
        const int cur = s & 1;
        const int s1 = (s + 1 < 64) ? s + 1 : 63;
        const int s2 = (s + 2 < 64) ? s + 2 : 63;
        const int Ts  = TILE(s);
        const int Ts1 = TILE(s1);
        const int Ts2 = TILE(s2);

        // deep prefetches first (stay in flight across the barrier)
        float4 vB = *reinterpret_cast<const float4*>(VADDR(Ts2) + goff);
        f32x4 uB = ntload4(UADDR(Ts1) + eoff);
        const float2 ms1 = stats[Ts1 >> 11];    // stats for the tile being staged

        // ---- MFMA over K=256 ----
        f32x4 acc = {0.f, 0.f, 0.f, 0.f};
        #pragma unroll
        for (int kb = 0; kb < 8; ++kb) {
            short8_t a = *reinterpret_cast<const short8_t*>(&vt[cur][aoff + kb * 32]);
            acc = __builtin_amdgcn_mfma_f32_16x16x32_bf16(a, bfrag[kb], acc, 0, 0, 0);
        }

        // ---- 4x4 transpose within lane quads: reg r <-> lane q ----
        float a0 = acc[0], a1 = acc[1], a2 = acc[2], a3 = acc[3];
        float s0 = __shfl_xor(a1, 1), s1v = __shfl_xor(a0, 1);
        float s2v = __shfl_xor(a3, 1), s3 = __shfl_xor(a2, 1);
        const bool qb0 = (q & 1);
        float w0 = qb0 ? s0 : a0;
        float w1 = qb0 ? a1 : s1v;
        float w2 = qb0 ? s2v : a2;
        float w3 = qb0 ? a3 : s3;
        float t0 = __shfl_xor(w2, 2), t1v = __shfl_xor(w3, 2);
        float t2v = __shfl_xor(w0, 2), t3 = __shfl_xor(w1, 2);
        const bool qb1 = (q & 2);
        float x0 = qb1 ? t0 : w0;
        float x1 = qb1 ? t1v : w1;
        float x2 = qb1 ? w2 : t2v;
        float x3 = qb1 ? w3 : t3;

        // ---- epilogue: out = u * (y + b + 1), non-temporal store ----
        f32x4 o;
        o[0] = uA[0] * (x0 + bq.x);
        o[1] = uA[1] * (x1 + bq.y);
        o[2] = uA[2] * (x2 + bq.z);
        o[3] = uA[3] * (x3 + bq.w);
        ntstore4(out + ((size_t)Ts << 12) + eoff, o);

        // ---- stage tile(s+1) (vA) into other buffer, with ITS batch stats ----
        short4 sn;
        sn.x = f2bf((vA.x - ms1.x) * ms1.y); sn.y = f2bf((vA.y - ms1.x) * ms1.y);
        sn.z = f2bf((vA.z - ms1.x) * ms1.y); sn.w = f2bf((vA.w - ms1.x) * ms1.y);
        *reinterpret_cast<short4*>(&vt[cur ^ 1][ldsw]) = sn;

        // raw barrier: drain LDS only, keep global loads in flight
        asm volatile("s_waitcnt lgkmcnt(0)" ::: "memory");
        __builtin_amdgcn_s_barrier();

        vA = vB; uA = uB;
    }
    #undef TILE
    #undef VADDR
    #undef UADDR
}

extern "C" void kernel_launch(void* const* d_in, const int* in_sizes, int n_in,
                              void* d_out, int out_size, void* d_ws, size_t ws_size,
                              hipStream_t stream) {
    const float* x    = (const float*)d_in[0];
    const float* W    = (const float*)d_in[1];
    const float* bias = (const float*)d_in[2];
    float* out = (float*)d_out;

    float2* partials = (float2*)d_ws;                       // 2048 * 8 B
    float2* stats    = (float2*)((char*)d_ws + 16384);      // 8 * 8 B

    stats_partial<<<2048, 256, 0, stream>>>(x, partials);
    stats_final<<<8, 256, 0, stream>>>(partials, stats);
    fused_gemm<<<256, 1024, 0, stream>>>(x, W, bias, stats, out);
}